// Round 11
// baseline (646.159 us; speedup 1.0000x reference)
//
#include <hip/hip_runtime.h>
#include <cstdint>
#include <math.h>

// EnergyCAModel: 4-step neural CA.
// x [B=16,H=128,W=128,C=16] f32. Out = x_steps [4*16*128*128*16] ++ fr_steps [4*16*128*128].
// R7 split-delivery structure + R11 software-pipelined L-row prefetch:
// each wave holds the NEXT pair's w0 (k0..31) in VGPRs (ping-pong X/Y),
// so the dot-product phase runs with zero lgkmcnt dependence on the
// just-issued ds_reads. LDS-pipe floor = 87us/step; R10 measured 134.
#define HW2    16384      // 128*128
#define BHW    262144     // 16*128*128
#define XSLICE 4194304    // BHW*16

__host__ __device__ static inline uint32_t rotl32(uint32_t v, int r) {
  return (v << r) | (v >> (32 - r));
}

// Exact JAX Threefry-2x32 (20 rounds), partitionable layout (verified R1).
__host__ __device__ static inline void tf2x32(uint32_t k0, uint32_t k1,
                                              uint32_t x0, uint32_t x1,
                                              uint32_t& o0, uint32_t& o1) {
  uint32_t ks2 = k0 ^ k1 ^ 0x1BD11BDAu;
  x0 += k0; x1 += k1;
#define TFR(r) { x0 += x1; x1 = rotl32(x1, (r)); x1 ^= x0; }
  TFR(13) TFR(15) TFR(26) TFR(6)   x0 += k1;  x1 += ks2 + 1u;
  TFR(17) TFR(29) TFR(16) TFR(24)  x0 += ks2; x1 += k0 + 2u;
  TFR(13) TFR(15) TFR(26) TFR(6)   x0 += k0;  x1 += k1 + 3u;
  TFR(17) TFR(29) TFR(16) TFR(24)  x0 += k1;  x1 += ks2 + 4u;
  TFR(13) TFR(15) TFR(26) TFR(6)   x0 += ks2; x1 += k0 + 5u;
#undef TFR
  o0 = x0; o1 = x1;
}

__device__ static inline float bits_to_unit(uint32_t bits) {
  return __uint_as_float((bits >> 9) | 0x3f800000u) - 1.0f;  // [0,1)
}

__device__ static inline uint32_t rng_bits(uint32_t sk0, uint32_t sk1, uint32_t f) {
  uint32_t o0, o1;
  tf2x32(sk0, sk1, 0u, f, o0, o1);
  return o0 ^ o1;
}

__device__ static inline float sigmoidf_(float z) {
  if (z >= 0.f) { float e = expf(-z); return 1.f / (1.f + e); }
  float e = expf(z); return e / (1.f + e);
}

// Sobel features + pre-alive max for one pixel.
__device__ static inline void sobel_feat(const float* __restrict__ base,
                                         int hh, int ww, float* dxv, float& m3) {
#pragma unroll
  for (int c = 0; c < 48; ++c) dxv[c] = 0.f;
  m3 = -INFINITY;
#pragma unroll
  for (int dh = -1; dh <= 1; ++dh) {
    const int j = dh + 1;
    const int h2 = hh + dh;
    const bool hok = ((unsigned)h2 < 128u);
#pragma unroll
    for (int dw = -1; dw <= 1; ++dw) {
      const int i = dw + 1;
      const int w2 = ww + dw;
      float v[16];
      if (hok && ((unsigned)w2 < 128u)) {
        const float* s = base + (((h2 << 7) + w2) << 4);
#pragma unroll
        for (int c = 0; c < 16; c += 4) {
          float4 q = *(const float4*)(s + c);
          v[c] = q.x; v[c + 1] = q.y; v[c + 2] = q.z; v[c + 3] = q.w;
        }
        m3 = fmaxf(m3, v[3]);
      } else {
#pragma unroll
        for (int c = 0; c < 16; ++c) v[c] = 0.f;
      }
      const float smv[3] = {1.f, 2.f, 1.f};
      const float dfv[3] = {-1.f, 0.f, 1.f};
      const float c1 = smv[i] * dfv[j] * 0.125f;  // y1
      const float c2 = dfv[i] * smv[j] * 0.125f;  // y2
      if (dh == 0 && dw == 0) {
#pragma unroll
        for (int c = 0; c < 16; ++c) dxv[c] = v[c];
      }
      if (c1 != 0.f) {
#pragma unroll
        for (int c = 0; c < 16; ++c) dxv[16 + c] = fmaf(c1, v[c], dxv[16 + c]);
      }
      if (c2 != 0.f) {
#pragma unroll
        for (int c = 0; c < 16; ++c) dxv[32 + c] = fmaf(c2, v[c], dxv[32 + c]);
      }
    }
  }
}

// 8 MACs of both pixels' dots against one float4 pair.
#define DOT8(wa, wb, k)                                                        \
  a00 = fmaf((wa).x, dx0[(k) + 0], a00); a01 = fmaf((wa).y, dx0[(k) + 1], a01);\
  a00 = fmaf((wa).z, dx0[(k) + 2], a00); a01 = fmaf((wa).w, dx0[(k) + 3], a01);\
  a00 = fmaf((wb).x, dx0[(k) + 4], a00); a01 = fmaf((wb).y, dx0[(k) + 5], a01);\
  a00 = fmaf((wb).z, dx0[(k) + 6], a00); a01 = fmaf((wb).w, dx0[(k) + 7], a01);\
  a10 = fmaf((wa).x, dx1[(k) + 0], a10); a11 = fmaf((wa).y, dx1[(k) + 1], a11);\
  a10 = fmaf((wa).z, dx1[(k) + 2], a10); a11 = fmaf((wa).w, dx1[(k) + 3], a11);\
  a10 = fmaf((wb).x, dx1[(k) + 4], a10); a11 = fmaf((wb).y, dx1[(k) + 5], a11);\
  a10 = fmaf((wb).z, dx1[(k) + 6], a10); a11 = fmaf((wb).w, dx1[(k) + 7], a11);

// One (L,S) neuron pair. CUR = prefetched w0 k0..31 of L-row I (8 float4);
// NXT is filled with row I+1's w0 k0..31 for the next body.
#define PAIR_BODY(CUR, NXT, I)                                                 \
  {                                                                            \
    const float4* crow = swr + (I) * 17;                                       \
    const float4 TL0 = crow[8],  TL1 = crow[9];   /* L w0 k32..39 */           \
    const float4 TL2 = crow[10], TL3 = crow[11];  /* L w0 k40..47 */           \
    const float4 W1q0 = crow[12], W1q1 = crow[13];                             \
    const float4 W1q2 = crow[14], W1q3 = crow[15];                             \
    const float bb = ((const float*)(crow + 16))[0];                           \
    const float4* nrow = swr + (((I) + 1) & 127) * 17;                         \
    _Pragma("unroll")                                                          \
    for (int q = 0; q < 8; ++q) NXT[q] = nrow[q];                              \
    const float* __restrict__ srow = pw + (size_t)(128 + (I)) * 68;            \
    float S[65];                                                               \
    _Pragma("unroll")                                                          \
    for (int q = 0; q < 65; ++q) S[q] = srow[q];                               \
    float a00 = 0.f, a01 = 0.f, a10 = 0.f, a11 = 0.f;                          \
    DOT8(CUR[0], CUR[1], 0)  DOT8(CUR[2], CUR[3], 8)                           \
    DOT8(CUR[4], CUR[5], 16) DOT8(CUR[6], CUR[7], 24)                          \
    DOT8(TL0, TL1, 32)       DOT8(TL2, TL3, 40)                                \
    const float r0 = fmaxf(bb + (a00 + a01), 0.f);                             \
    const float r1 = fmaxf(bb + (a10 + a11), 0.f);                             \
    {                                                                          \
      const float w1v[16] = {W1q0.x, W1q0.y, W1q0.z, W1q0.w,                   \
                             W1q1.x, W1q1.y, W1q1.z, W1q1.w,                   \
                             W1q2.x, W1q2.y, W1q2.z, W1q2.w,                   \
                             W1q3.x, W1q3.y, W1q3.z, W1q3.w};                  \
      _Pragma("unroll")                                                        \
      for (int c = 0; c < 16; ++c) {                                           \
        h0[c] = fmaf(w1v[c], r0, h0[c]);                                       \
        h1[c] = fmaf(w1v[c], r1, h1[c]);                                       \
      }                                                                        \
    }                                                                          \
    {                                                                          \
      float b00 = 0.f, b01 = 0.f, b10 = 0.f, b11 = 0.f;                        \
      _Pragma("unroll")                                                        \
      for (int k = 0; k < 48; k += 2) {                                        \
        b00 = fmaf(S[k], dx0[k], b00);   b01 = fmaf(S[k + 1], dx0[k + 1], b01);\
        b10 = fmaf(S[k], dx1[k], b10);   b11 = fmaf(S[k + 1], dx1[k + 1], b11);\
      }                                                                        \
      const float sbb = S[64];                                                 \
      const float s0 = fmaxf(sbb + (b00 + b01), 0.f);                          \
      const float s1 = fmaxf(sbb + (b10 + b11), 0.f);                          \
      _Pragma("unroll")                                                        \
      for (int c = 0; c < 16; ++c) {                                           \
        h0[c] = fmaf(S[48 + c], s0, h0[c]);                                    \
        h1[c] = fmaf(S[48 + c], s1, h1[c]);                                    \
      }                                                                        \
    }                                                                          \
  }

// Kernel A: 2 pixels/thread; split weight delivery + pipelined L-row.
__global__ __launch_bounds__(256, 2) void ca_step_a(
    const float* __restrict__ xin,   // [B,H,W,16]
    const float* __restrict__ pw,    // [256][68] packed rows: w0(48)|w1t(16)|b0|pad3
    const float* __restrict__ wfrg,  // [48]
    float* __restrict__ xmid,
    float* __restrict__ ch3,
    float* __restrict__ premask,
    float* __restrict__ frout,
    uint32_t sk0, uint32_t sk1) {
  __shared__ float sw[128 * 68];   // 34.8 KB: rows 0..127

  const int tid = threadIdx.x;
  {
    const float4* src = (const float4*)pw;   // rows 0..127 = first 2176 float4
    float4* dst = (float4*)sw;
    for (int i = tid; i < 2176; i += 256) dst[i] = src[i];
  }
  __syncthreads();

  const int p0  = blockIdx.x * 512 + tid;
  const int p1  = p0 + 256;
  const int b   = p0 >> 14;
  const int rem = p0 & 16383;
  const int hh0 = rem >> 7;
  const int ww0 = rem & 127;
  const int hh1 = hh0 + 2;          // p1 = p0 + 256 -> +2 rows

  const float* base = xin + ((size_t)b << 18);

  float dx0[48], dx1[48];
  float m30, m31;
  sobel_feat(base, hh0, ww0, dx0, m30);
  sobel_feat(base, hh1, ww0, dx1, m31);

  const bool pre0 = (m30 > 0.1f);
  const bool pre1 = (m31 > 0.1f);

  float z0 = 0.f, z1 = 0.f;
#pragma unroll
  for (int c = 0; c < 48; ++c) {
    z0 = fmaf(dx0[c], wfrg[c], z0);
    z1 = fmaf(dx1[c], wfrg[c], z1);
  }
  const float fr0 = pre0 ? sigmoidf_(z0) : 0.f;
  const float fr1 = pre1 ? sigmoidf_(z1) : 0.f;

  float upd0, upd1;
  {
    const float u0 = bits_to_unit(rng_bits(sk0, sk1, 2u * (uint32_t)p0));
    const float u1 = bits_to_unit(rng_bits(sk0, sk1, 2u * (uint32_t)p0 + 1u));
    const float d0 = logf(fr0 + 1e-10f) - logf(-logf(u0 + 1e-20f) + 1e-20f);
    const float d1 = logf(1.0f - fr0 + 1e-10f) - logf(-logf(u1 + 1e-20f) + 1e-20f);
    upd0 = (d0 >= d1) ? 1.f : 0.f;
  }
  {
    const float u0 = bits_to_unit(rng_bits(sk0, sk1, 2u * (uint32_t)p1));
    const float u1 = bits_to_unit(rng_bits(sk0, sk1, 2u * (uint32_t)p1 + 1u));
    const float d0 = logf(fr1 + 1e-10f) - logf(-logf(u0 + 1e-20f) + 1e-20f);
    const float d1 = logf(1.0f - fr1 + 1e-10f) - logf(-logf(u1 + 1e-20f) + 1e-20f);
    upd1 = (d0 >= d1) ? 1.f : 0.f;
  }

  float h0[16], h1[16];
#pragma unroll
  for (int c = 0; c < 16; ++c) { h0[c] = 0.f; h1[c] = 0.f; }

  const float4* swr = (const float4*)sw;
  float4 X[8], Y[8];
#pragma unroll
  for (int q = 0; q < 8; ++q) X[q] = swr[q];   // preload row 0, k0..31

  for (int i = 0; i < 128; i += 2) {
    PAIR_BODY(X, Y, i)
    PAIR_BODY(Y, X, i + 1)
  }

  float* dst0 = xmid + ((size_t)p0 << 4);
  float* dst1 = xmid + ((size_t)p1 << 4);
#pragma unroll
  for (int c = 0; c < 16; c += 4) {
    float4 q0, q1;
    q0.x = fmaf(upd0, h0[c],     dx0[c]);     q1.x = fmaf(upd1, h1[c],     dx1[c]);
    q0.y = fmaf(upd0, h0[c + 1], dx0[c + 1]); q1.y = fmaf(upd1, h1[c + 1], dx1[c + 1]);
    q0.z = fmaf(upd0, h0[c + 2], dx0[c + 2]); q1.z = fmaf(upd1, h1[c + 2], dx1[c + 2]);
    q0.w = fmaf(upd0, h0[c + 3], dx0[c + 3]); q1.w = fmaf(upd1, h1[c + 3], dx1[c + 3]);
    *(float4*)(dst0 + c) = q0;
    *(float4*)(dst1 + c) = q1;
  }
  ch3[p0]     = fmaf(upd0, h0[3], dx0[3]);
  ch3[p1]     = fmaf(upd1, h1[3], dx1[3]);
  premask[p0] = pre0 ? 1.f : 0.f;
  premask[p1] = pre1 ? 1.f : 0.f;
  frout[p0]   = fr0;
  frout[p1]   = fr1;
}

// Kernel B: post-alive mask; zero dead pixels in-place in the d_out slice.
__global__ __launch_bounds__(256) void ca_step_b(
    float* __restrict__ xs, const float* __restrict__ ch3,
    const float* __restrict__ premask) {
  const int p   = blockIdx.x * 256 + threadIdx.x;
  const int b   = p >> 14;
  const int rem = p & 16383;
  const int hh  = rem >> 7;
  const int ww  = rem & 127;

  const bool prea = (premask[p] != 0.f);
  bool alive = false;
  if (prea) {
    const float* cb = ch3 + (b << 14);
    float m = -INFINITY;
#pragma unroll
    for (int dh = -1; dh <= 1; ++dh) {
      const int h2 = hh + dh;
      if ((unsigned)h2 >= 128u) continue;
#pragma unroll
      for (int dw = -1; dw <= 1; ++dw) {
        const int w2 = ww + dw;
        if ((unsigned)w2 >= 128u) continue;
        m = fmaxf(m, cb[(h2 << 7) + w2]);
      }
    }
    alive = (m > 0.1f);
  }
  if (!alive) {
    float4 z; z.x = 0.f; z.y = 0.f; z.z = 0.f; z.w = 0.f;
    float* dst = xs + ((size_t)p << 4);
    *(float4*)(dst)      = z;
    *(float4*)(dst + 4)  = z;
    *(float4*)(dst + 8)  = z;
    *(float4*)(dst + 12) = z;
  }
}

// Pack per-neuron rows: [w0 row(48) | w1t(16) | b0 | pad3] stride 68.
__global__ void pack_weights(const float* __restrict__ w0,
                             const float* __restrict__ b0,
                             const float* __restrict__ w1,
                             float* __restrict__ pw) {
  const int j = blockIdx.x * 256 + threadIdx.x;
  if (j < 256) {
    float* r = pw + j * 68;
#pragma unroll
    for (int k = 0; k < 48; ++k) r[k] = w0[j * 48 + k];
#pragma unroll
    for (int c = 0; c < 16; ++c) r[48 + c] = w1[c * 256 + j];
    r[64] = b0[j];
    r[65] = 0.f; r[66] = 0.f; r[67] = 0.f;
  }
}

extern "C" void kernel_launch(void* const* d_in, const int* in_sizes, int n_in,
                              void* d_out, int out_size, void* d_ws, size_t ws_size,
                              hipStream_t stream) {
  const float* x0  = (const float*)d_in[0];
  const float* w0  = (const float*)d_in[1];
  const float* b0  = (const float*)d_in[2];
  const float* w1  = (const float*)d_in[3];
  const float* wfr = (const float*)d_in[4];
  const int steps = 4;

  float* xsteps  = (float*)d_out;
  float* frsteps = xsteps + (size_t)steps * XSLICE;

  float* pw  = (float*)d_ws;        // 17408 f
  float* ch3 = pw + 17408;          // BHW f
  float* pre = ch3 + BHW;           // BHW f

  // step keys = jax.random.split(jax.random.key(42), 4) (partitionable threefry)
  uint32_t sk[4][2];
  for (int s = 0; s < steps; ++s)
    tf2x32(0u, 42u, 0u, (uint32_t)s, sk[s][0], sk[s][1]);

  pack_weights<<<1, 256, 0, stream>>>(w0, b0, w1, pw);
  for (int s = 0; s < steps; ++s) {
    const float* xin = (s == 0) ? x0 : (xsteps + (size_t)(s - 1) * XSLICE);
    float* xmid = xsteps + (size_t)s * XSLICE;
    ca_step_a<<<512, 256, 0, stream>>>(xin, pw, wfr, xmid, ch3, pre,
                                       frsteps + (size_t)s * BHW, sk[s][0], sk[s][1]);
    ca_step_b<<<1024, 256, 0, stream>>>(xmid, ch3, pre);
  }
}

// Round 12
// 460.499 us; speedup vs baseline: 1.4032x; 1.4032x over previous
//
#include <hip/hip_runtime.h>
#include <cstdint>
#include <math.h>

// EnergyCAModel: 4-step neural CA.
// x [B=16,H=128,W=128,C=16] f32. Out = x_steps [4*16*128*128*16] ++ fr_steps [4*16*128*128].
// CHAMPION (R7/R10, 462us, reproduced 2x): split weight delivery at the
// LDS/scalar pipe balance point. L-neurons 0..127 fully from LDS broadcast
// (17 b128/pair); S-neurons 128..255 fully from the scalar pipe (65-float
// uniform row consumed last, latency covered by the L-neuron's work).
// Escapes tested and regressed: more-scalar (R8), sparsity (R9), P=4 (R6),
// VMEM (R4), SW-pipeline (R11, VGPR-cap spill). Delivery pipes balanced.
#define HW2    16384      // 128*128
#define BHW    262144     // 16*128*128
#define XSLICE 4194304    // BHW*16

__host__ __device__ static inline uint32_t rotl32(uint32_t v, int r) {
  return (v << r) | (v >> (32 - r));
}

// Exact JAX Threefry-2x32 (20 rounds), partitionable layout (verified R1).
__host__ __device__ static inline void tf2x32(uint32_t k0, uint32_t k1,
                                              uint32_t x0, uint32_t x1,
                                              uint32_t& o0, uint32_t& o1) {
  uint32_t ks2 = k0 ^ k1 ^ 0x1BD11BDAu;
  x0 += k0; x1 += k1;
#define TFR(r) { x0 += x1; x1 = rotl32(x1, (r)); x1 ^= x0; }
  TFR(13) TFR(15) TFR(26) TFR(6)   x0 += k1;  x1 += ks2 + 1u;
  TFR(17) TFR(29) TFR(16) TFR(24)  x0 += ks2; x1 += k0 + 2u;
  TFR(13) TFR(15) TFR(26) TFR(6)   x0 += k0;  x1 += k1 + 3u;
  TFR(17) TFR(29) TFR(16) TFR(24)  x0 += k1;  x1 += ks2 + 4u;
  TFR(13) TFR(15) TFR(26) TFR(6)   x0 += ks2; x1 += k0 + 5u;
#undef TFR
  o0 = x0; o1 = x1;
}

__device__ static inline float bits_to_unit(uint32_t bits) {
  return __uint_as_float((bits >> 9) | 0x3f800000u) - 1.0f;  // [0,1)
}

__device__ static inline uint32_t rng_bits(uint32_t sk0, uint32_t sk1, uint32_t f) {
  uint32_t o0, o1;
  tf2x32(sk0, sk1, 0u, f, o0, o1);
  return o0 ^ o1;
}

__device__ static inline float sigmoidf_(float z) {
  if (z >= 0.f) { float e = expf(-z); return 1.f / (1.f + e); }
  float e = expf(z); return e / (1.f + e);
}

// Sobel features + pre-alive max for one pixel.
__device__ static inline void sobel_feat(const float* __restrict__ base,
                                         int hh, int ww, float* dxv, float& m3) {
#pragma unroll
  for (int c = 0; c < 48; ++c) dxv[c] = 0.f;
  m3 = -INFINITY;
#pragma unroll
  for (int dh = -1; dh <= 1; ++dh) {
    const int j = dh + 1;
    const int h2 = hh + dh;
    const bool hok = ((unsigned)h2 < 128u);
#pragma unroll
    for (int dw = -1; dw <= 1; ++dw) {
      const int i = dw + 1;
      const int w2 = ww + dw;
      float v[16];
      if (hok && ((unsigned)w2 < 128u)) {
        const float* s = base + (((h2 << 7) + w2) << 4);
#pragma unroll
        for (int c = 0; c < 16; c += 4) {
          float4 q = *(const float4*)(s + c);
          v[c] = q.x; v[c + 1] = q.y; v[c + 2] = q.z; v[c + 3] = q.w;
        }
        m3 = fmaxf(m3, v[3]);
      } else {
#pragma unroll
        for (int c = 0; c < 16; ++c) v[c] = 0.f;
      }
      const float smv[3] = {1.f, 2.f, 1.f};
      const float dfv[3] = {-1.f, 0.f, 1.f};
      const float c1 = smv[i] * dfv[j] * 0.125f;  // y1
      const float c2 = dfv[i] * smv[j] * 0.125f;  // y2
      if (dh == 0 && dw == 0) {
#pragma unroll
        for (int c = 0; c < 16; ++c) dxv[c] = v[c];
      }
      if (c1 != 0.f) {
#pragma unroll
        for (int c = 0; c < 16; ++c) dxv[16 + c] = fmaf(c1, v[c], dxv[16 + c]);
      }
      if (c2 != 0.f) {
#pragma unroll
        for (int c = 0; c < 16; ++c) dxv[32 + c] = fmaf(c2, v[c], dxv[32 + c]);
      }
    }
  }
}

// Kernel A: 2 pixels/thread; split weight delivery (R7-v1, validated best).
__global__ __launch_bounds__(256, 2) void ca_step_a(
    const float* __restrict__ xin,   // [B,H,W,16]
    const float* __restrict__ pw,    // [256][68] packed rows: w0(48)|w1t(16)|b0|pad3
    const float* __restrict__ wfrg,  // [48]
    float* __restrict__ xmid,
    float* __restrict__ ch3,
    float* __restrict__ premask,
    float* __restrict__ frout,
    uint32_t sk0, uint32_t sk1) {
  __shared__ float sw[128 * 68];   // 34.8 KB: rows 0..127

  const int tid = threadIdx.x;
  {
    const float4* src = (const float4*)pw;   // rows 0..127 = first 2176 float4
    float4* dst = (float4*)sw;
    for (int i = tid; i < 2176; i += 256) dst[i] = src[i];
  }
  __syncthreads();

  const int p0  = blockIdx.x * 512 + tid;
  const int p1  = p0 + 256;
  const int b   = p0 >> 14;
  const int rem = p0 & 16383;
  const int hh0 = rem >> 7;
  const int ww0 = rem & 127;
  const int hh1 = hh0 + 2;          // p1 = p0 + 256 -> +2 rows

  const float* base = xin + ((size_t)b << 18);

  float dx0[48], dx1[48];
  float m30, m31;
  sobel_feat(base, hh0, ww0, dx0, m30);
  sobel_feat(base, hh1, ww0, dx1, m31);

  const bool pre0 = (m30 > 0.1f);
  const bool pre1 = (m31 > 0.1f);

  float z0 = 0.f, z1 = 0.f;
#pragma unroll
  for (int c = 0; c < 48; ++c) {
    z0 = fmaf(dx0[c], wfrg[c], z0);
    z1 = fmaf(dx1[c], wfrg[c], z1);
  }
  const float fr0 = pre0 ? sigmoidf_(z0) : 0.f;
  const float fr1 = pre1 ? sigmoidf_(z1) : 0.f;

  float upd0, upd1;
  {
    const float u0 = bits_to_unit(rng_bits(sk0, sk1, 2u * (uint32_t)p0));
    const float u1 = bits_to_unit(rng_bits(sk0, sk1, 2u * (uint32_t)p0 + 1u));
    const float d0 = logf(fr0 + 1e-10f) - logf(-logf(u0 + 1e-20f) + 1e-20f);
    const float d1 = logf(1.0f - fr0 + 1e-10f) - logf(-logf(u1 + 1e-20f) + 1e-20f);
    upd0 = (d0 >= d1) ? 1.f : 0.f;
  }
  {
    const float u0 = bits_to_unit(rng_bits(sk0, sk1, 2u * (uint32_t)p1));
    const float u1 = bits_to_unit(rng_bits(sk0, sk1, 2u * (uint32_t)p1 + 1u));
    const float d0 = logf(fr1 + 1e-10f) - logf(-logf(u0 + 1e-20f) + 1e-20f);
    const float d1 = logf(1.0f - fr1 + 1e-10f) - logf(-logf(u1 + 1e-20f) + 1e-20f);
    upd1 = (d0 >= d1) ? 1.f : 0.f;
  }

  float h0[16], h1[16];
#pragma unroll
  for (int c = 0; c < 16; ++c) { h0[c] = 0.f; h1[c] = 0.f; }

  for (int i = 0; i < 128; ++i) {
    // ---- issue scalar row (neuron 128+i) first: uniform -> s_load ----
    const float* __restrict__ srow = pw + (size_t)(128 + i) * 68;
    float S[65];
#pragma unroll
    for (int q = 0; q < 65; ++q) S[q] = srow[q];

    // ---- L-neuron i from LDS (ds_read drain covers the s_load latency) ----
    {
      const float* row = sw + i * 68;
      float a00 = 0.f, a01 = 0.f, a10 = 0.f, a11 = 0.f;
#pragma unroll
      for (int ks = 0; ks < 6; ++ks) {
        const int k = ks * 8;
        const float4 wa = *(const float4*)(row + k);
        const float4 wb = *(const float4*)(row + k + 4);
        a00 = fmaf(wa.x, dx0[k + 0], a00); a01 = fmaf(wa.y, dx0[k + 1], a01);
        a00 = fmaf(wa.z, dx0[k + 2], a00); a01 = fmaf(wa.w, dx0[k + 3], a01);
        a00 = fmaf(wb.x, dx0[k + 4], a00); a01 = fmaf(wb.y, dx0[k + 5], a01);
        a00 = fmaf(wb.z, dx0[k + 6], a00); a01 = fmaf(wb.w, dx0[k + 7], a01);
        a10 = fmaf(wa.x, dx1[k + 0], a10); a11 = fmaf(wa.y, dx1[k + 1], a11);
        a10 = fmaf(wa.z, dx1[k + 2], a10); a11 = fmaf(wa.w, dx1[k + 3], a11);
        a10 = fmaf(wb.x, dx1[k + 4], a10); a11 = fmaf(wb.y, dx1[k + 5], a11);
        a10 = fmaf(wb.z, dx1[k + 6], a10); a11 = fmaf(wb.w, dx1[k + 7], a11);
      }
      const float bb = row[64];
      const float r0 = fmaxf(bb + (a00 + a01), 0.f);
      const float r1 = fmaxf(bb + (a10 + a11), 0.f);
#pragma unroll
      for (int c4 = 0; c4 < 4; ++c4) {
        const float4 q = *(const float4*)(row + 48 + (c4 << 2));
        const int c = c4 << 2;
        h0[c]     = fmaf(q.x, r0, h0[c]);     h1[c]     = fmaf(q.x, r1, h1[c]);
        h0[c + 1] = fmaf(q.y, r0, h0[c + 1]); h1[c + 1] = fmaf(q.y, r1, h1[c + 1]);
        h0[c + 2] = fmaf(q.z, r0, h0[c + 2]); h1[c + 2] = fmaf(q.z, r1, h1[c + 2]);
        h0[c + 3] = fmaf(q.w, r0, h0[c + 3]); h1[c + 3] = fmaf(q.w, r1, h1[c + 3]);
      }
    }

    // ---- S-neuron 128+i from SGPRs (zero LDS traffic, consumed last) ----
    {
      float a00 = 0.f, a01 = 0.f, a10 = 0.f, a11 = 0.f;
#pragma unroll
      for (int k = 0; k < 48; k += 2) {
        a00 = fmaf(S[k], dx0[k], a00);     a01 = fmaf(S[k + 1], dx0[k + 1], a01);
        a10 = fmaf(S[k], dx1[k], a10);     a11 = fmaf(S[k + 1], dx1[k + 1], a11);
      }
      const float bb = S[64];
      const float r0 = fmaxf(bb + (a00 + a01), 0.f);
      const float r1 = fmaxf(bb + (a10 + a11), 0.f);
#pragma unroll
      for (int c = 0; c < 16; ++c) {
        h0[c] = fmaf(S[48 + c], r0, h0[c]);
        h1[c] = fmaf(S[48 + c], r1, h1[c]);
      }
    }
  }

  float* dst0 = xmid + ((size_t)p0 << 4);
  float* dst1 = xmid + ((size_t)p1 << 4);
#pragma unroll
  for (int c = 0; c < 16; c += 4) {
    float4 q0, q1;
    q0.x = fmaf(upd0, h0[c],     dx0[c]);     q1.x = fmaf(upd1, h1[c],     dx1[c]);
    q0.y = fmaf(upd0, h0[c + 1], dx0[c + 1]); q1.y = fmaf(upd1, h1[c + 1], dx1[c + 1]);
    q0.z = fmaf(upd0, h0[c + 2], dx0[c + 2]); q1.z = fmaf(upd1, h1[c + 2], dx1[c + 2]);
    q0.w = fmaf(upd0, h0[c + 3], dx0[c + 3]); q1.w = fmaf(upd1, h1[c + 3], dx1[c + 3]);
    *(float4*)(dst0 + c) = q0;
    *(float4*)(dst1 + c) = q1;
  }
  ch3[p0]     = fmaf(upd0, h0[3], dx0[3]);
  ch3[p1]     = fmaf(upd1, h1[3], dx1[3]);
  premask[p0] = pre0 ? 1.f : 0.f;
  premask[p1] = pre1 ? 1.f : 0.f;
  frout[p0]   = fr0;
  frout[p1]   = fr1;
}

// Kernel B: post-alive mask; zero dead pixels in-place in the d_out slice.
// Early-exit on premask==0 (skip the 9 ch3 loads).
__global__ __launch_bounds__(256) void ca_step_b(
    float* __restrict__ xs, const float* __restrict__ ch3,
    const float* __restrict__ premask) {
  const int p   = blockIdx.x * 256 + threadIdx.x;
  const int b   = p >> 14;
  const int rem = p & 16383;
  const int hh  = rem >> 7;
  const int ww  = rem & 127;

  const bool prea = (premask[p] != 0.f);
  bool alive = false;
  if (prea) {
    const float* cb = ch3 + (b << 14);
    float m = -INFINITY;
#pragma unroll
    for (int dh = -1; dh <= 1; ++dh) {
      const int h2 = hh + dh;
      if ((unsigned)h2 >= 128u) continue;
#pragma unroll
      for (int dw = -1; dw <= 1; ++dw) {
        const int w2 = ww + dw;
        if ((unsigned)w2 >= 128u) continue;
        m = fmaxf(m, cb[(h2 << 7) + w2]);
      }
    }
    alive = (m > 0.1f);
  }
  if (!alive) {
    float4 z; z.x = 0.f; z.y = 0.f; z.z = 0.f; z.w = 0.f;
    float* dst = xs + ((size_t)p << 4);
    *(float4*)(dst)      = z;
    *(float4*)(dst + 4)  = z;
    *(float4*)(dst + 8)  = z;
    *(float4*)(dst + 12) = z;
  }
}

// Pack per-neuron rows: [w0 row(48) | w1t(16) | b0 | pad3] stride 68.
__global__ void pack_weights(const float* __restrict__ w0,
                             const float* __restrict__ b0,
                             const float* __restrict__ w1,
                             float* __restrict__ pw) {
  const int j = blockIdx.x * 256 + threadIdx.x;
  if (j < 256) {
    float* r = pw + j * 68;
#pragma unroll
    for (int k = 0; k < 48; ++k) r[k] = w0[j * 48 + k];
#pragma unroll
    for (int c = 0; c < 16; ++c) r[48 + c] = w1[c * 256 + j];
    r[64] = b0[j];
    r[65] = 0.f; r[66] = 0.f; r[67] = 0.f;
  }
}

extern "C" void kernel_launch(void* const* d_in, const int* in_sizes, int n_in,
                              void* d_out, int out_size, void* d_ws, size_t ws_size,
                              hipStream_t stream) {
  const float* x0  = (const float*)d_in[0];
  const float* w0  = (const float*)d_in[1];
  const float* b0  = (const float*)d_in[2];
  const float* w1  = (const float*)d_in[3];
  const float* wfr = (const float*)d_in[4];
  const int steps = 4;

  float* xsteps  = (float*)d_out;
  float* frsteps = xsteps + (size_t)steps * XSLICE;

  float* pw  = (float*)d_ws;        // 17408 f
  float* ch3 = pw + 17408;          // BHW f
  float* pre = ch3 + BHW;           // BHW f

  // step keys = jax.random.split(jax.random.key(42), 4) (partitionable threefry)
  uint32_t sk[4][2];
  for (int s = 0; s < steps; ++s)
    tf2x32(0u, 42u, 0u, (uint32_t)s, sk[s][0], sk[s][1]);

  pack_weights<<<1, 256, 0, stream>>>(w0, b0, w1, pw);
  for (int s = 0; s < steps; ++s) {
    const float* xin = (s == 0) ? x0 : (xsteps + (size_t)(s - 1) * XSLICE);
    float* xmid = xsteps + (size_t)s * XSLICE;
    ca_step_a<<<512, 256, 0, stream>>>(xin, pw, wfr, xmid, ch3, pre,
                                       frsteps + (size_t)s * BHW, sk[s][0], sk[s][1]);
    ca_step_b<<<1024, 256, 0, stream>>>(xmid, ch3, pre);
  }
}